// Round 6
// baseline (300.189 us; speedup 1.0000x reference)
//
#include <hip/hip_runtime.h>

// patient_GCN: 2x GCNConv(128->128) + mean-pool + head.
// R6: gathered buffers (GEMM outputs, pre-scaled by dinv) stored as fp8 e4m3
// -> 128 B rows, halves cross-XCD L2-fill traffic in agg; 8 edges per wave pass.
// fp32 accumulation; agg outputs bf16 (dense consumers).

#define NFEAT 128
#define NPB 128  // nodes per pool block

typedef __attribute__((ext_vector_type(8))) short bf16x8;
typedef __attribute__((ext_vector_type(4))) float f32x4;
typedef __attribute__((ext_vector_type(2))) float f32x2;

static __device__ __forceinline__ unsigned short f2bf(float f) {
  unsigned u = __float_as_uint(f);
  return (unsigned short)((u + 0x7fffu + ((u >> 16) & 1u)) >> 16);
}
static __device__ __forceinline__ unsigned pack2(float a, float b) {
  return (unsigned)f2bf(a) | ((unsigned)f2bf(b) << 16);
}
static __device__ __forceinline__ unsigned char f2fp8(float v) {
  return (unsigned char)(__builtin_amdgcn_cvt_pk_fp8_f32(v, 0.f, 0, false) & 0xff);
}
// decode 16 fp8 (uint4) and add into acc[0..15]
static __device__ __forceinline__ void add16(float* a, uint4 h) {
  f32x2 t;
  t = __builtin_amdgcn_cvt_pk_f32_fp8(h.x, false); a[0] += t[0]; a[1] += t[1];
  t = __builtin_amdgcn_cvt_pk_f32_fp8(h.x, true);  a[2] += t[0]; a[3] += t[1];
  t = __builtin_amdgcn_cvt_pk_f32_fp8(h.y, false); a[4] += t[0]; a[5] += t[1];
  t = __builtin_amdgcn_cvt_pk_f32_fp8(h.y, true);  a[6] += t[0]; a[7] += t[1];
  t = __builtin_amdgcn_cvt_pk_f32_fp8(h.z, false); a[8] += t[0]; a[9] += t[1];
  t = __builtin_amdgcn_cvt_pk_f32_fp8(h.z, true);  a[10] += t[0]; a[11] += t[1];
  t = __builtin_amdgcn_cvt_pk_f32_fp8(h.w, false); a[12] += t[0]; a[13] += t[1];
  t = __builtin_amdgcn_cvt_pk_f32_fp8(h.w, true);  a[14] += t[0]; a[15] += t[1];
}

// ---------------- prep: zero cnt+ps, transpose W1/W2 to bf16, graph bounds ----
__global__ void k_prep(const float* __restrict__ W1, const float* __restrict__ W2,
                       unsigned short* __restrict__ WT1, unsigned short* __restrict__ WT2,
                       const int* __restrict__ batch, int* __restrict__ gstart,
                       int* __restrict__ cnt, float* __restrict__ ps,
                       int n, int G, int nb_cnt, int nb_ps) {
  int b = blockIdx.x, t = threadIdx.x;
  if (b < nb_cnt) {
    int i = b * 256 + t;
    if (i < n) cnt[i] = 0;
  } else if (b < nb_cnt + nb_ps) {
    int i = (b - nb_cnt) * 256 + t;
    if (i < G * 128) ps[i] = 0.f;
  } else if (b < nb_cnt + nb_ps + 128) {
    int e = (b - nb_cnt - nb_ps) * 256 + t;  // 32768 total
    int w = e >> 14;
    int r = (e >> 7) & 127, k = e & 127;
    if (w == 0) WT1[r * 128 + k] = f2bf(W1[k * 128 + r]);
    else        WT2[r * 128 + k] = f2bf(W2[k * 128 + r]);
  } else {
    int g = (b - nb_cnt - nb_ps - 128) * 256 + t;
    if (g > G) return;
    if (g == G) { gstart[g] = n; return; }
    int lo = 0, hi = n;
    while (lo < hi) {
      int mid = (lo + hi) >> 1;
      if (batch[mid] < g) lo = mid + 1; else hi = mid;
    }
    gstart[g] = lo;
  }
}

// ---------------- CSR build ----------------
__global__ void k_deg(const int* __restrict__ dst, int* __restrict__ cnt, int E) {
  int e = blockIdx.x * 256 + threadIdx.x;
  if (e < E) atomicAdd(&cnt[dst[e]], 1);
}

__global__ void k_part(const int* __restrict__ cnt, int* __restrict__ part, int n) {
  __shared__ int s[256];
  int t = threadIdx.x;
  int idx = blockIdx.x * 256 + t;
  s[t] = (idx < n) ? cnt[idx] : 0;
  __syncthreads();
  for (int o = 128; o > 0; o >>= 1) {
    if (t < o) s[t] += s[t + o];
    __syncthreads();
  }
  if (t == 0) part[blockIdx.x] = s[0];
}

__global__ void k_scan1(const int* __restrict__ part, int* __restrict__ ppre,
                        int NB, int* __restrict__ offs, int n) {
  __shared__ int s[256];
  int t = threadIdx.x;
  int v = (t < NB) ? part[t] : 0;
  s[t] = v;
  __syncthreads();
  for (int o = 1; o < 256; o <<= 1) {
    int tmp = (t >= o) ? s[t - o] : 0;
    __syncthreads();
    s[t] += tmp;
    __syncthreads();
  }
  if (t < NB) ppre[t] = s[t] - v;
  if (t == NB - 1) offs[n] = s[t];
}

__global__ void k_offsets(const int* __restrict__ cnt, const int* __restrict__ ppre,
                          int* __restrict__ offs, int* __restrict__ cursor,
                          float* __restrict__ dinv, int n) {
  __shared__ int s[256];
  int t = threadIdx.x;
  int idx = blockIdx.x * 256 + t;
  int v = (idx < n) ? cnt[idx] : 0;
  s[t] = v;
  __syncthreads();
  for (int o = 1; o < 256; o <<= 1) {
    int tmp = (t >= o) ? s[t - o] : 0;
    __syncthreads();
    s[t] += tmp;
    __syncthreads();
  }
  if (idx < n) {
    int off = ppre[blockIdx.x] + s[t] - v;
    offs[idx] = off;
    cursor[idx] = off;
    dinv[idx] = rsqrtf((float)(v + 1));
  }
}

__global__ void k_fill(const int* __restrict__ src, const int* __restrict__ dst,
                       int* __restrict__ cursor, int* __restrict__ csr, int E) {
  int e = blockIdx.x * 256 + threadIdx.x;
  if (e < E) {
    int p = atomicAdd(&cursor[dst[e]], 1);
    csr[p] = src[e];
  }
}

// ---------------- GEMM: Hs[M,128](fp8) = dinv[m] * (X[M,128] @ W) ----------------
template <bool FP32IN>
__global__ __launch_bounds__(256) void k_gemm_mfma(const void* __restrict__ Xv,
                                                   const uint4* __restrict__ WT4,
                                                   const float* __restrict__ dinv,
                                                   unsigned char* __restrict__ H8,
                                                   int M) {
  __shared__ __align__(16) unsigned short sW[128 * 136];
  __shared__ __align__(16) unsigned short sX[64 * 136];
  int tid = threadIdx.x;
  int m0 = blockIdx.x * 64;

#pragma unroll
  for (int t = 0; t < 8; t++) {
    int idx = tid + t * 256;
    int n = idx >> 4, c8 = idx & 15;
    *(uint4*)(sW + n * 136 + c8 * 8) = WT4[idx];
  }
  if (FP32IN) {
    const float4* X4 = (const float4*)Xv;
#pragma unroll
    for (int t = 0; t < 8; t++) {
      int idx = tid + t * 256;
      int r = idx >> 5, c4 = idx & 31;
      int m = m0 + r;
      float4 v = make_float4(0.f, 0.f, 0.f, 0.f);
      if (m < M) v = X4[(size_t)m * 32 + c4];
      unsigned short* p = sX + r * 136 + c4 * 4;
      *(ushort2*)(p) = make_ushort2(f2bf(v.x), f2bf(v.y));
      *(ushort2*)(p + 2) = make_ushort2(f2bf(v.z), f2bf(v.w));
    }
  } else {
    const uint4* X4 = (const uint4*)Xv;
#pragma unroll
    for (int t = 0; t < 4; t++) {
      int idx = tid + t * 256;
      int r = idx >> 4, c8 = idx & 15;
      int m = m0 + r;
      uint4 v = make_uint4(0u, 0u, 0u, 0u);
      if (m < M) v = X4[(size_t)m * 16 + c8];
      *(uint4*)(sX + r * 136 + c8 * 8) = v;
    }
  }
  __syncthreads();

  int lane = tid & 63, wv = tid >> 6;
  int ln15 = lane & 15, q = lane >> 4;
  bf16x8 afrag[4];
#pragma unroll
  for (int c = 0; c < 4; c++)
    afrag[c] = *(const bf16x8*)(sX + (wv * 16 + ln15) * 136 + c * 32 + q * 8);

  int r0 = m0 + wv * 16 + q * 4;
  float dv[4];
#pragma unroll
  for (int rr = 0; rr < 4; rr++) dv[rr] = (r0 + rr < M) ? dinv[r0 + rr] : 0.f;

#pragma unroll
  for (int j = 0; j < 8; j++) {
    f32x4 acc = {0.f, 0.f, 0.f, 0.f};
#pragma unroll
    for (int c = 0; c < 4; c++) {
      bf16x8 bfrag = *(const bf16x8*)(sW + (j * 16 + ln15) * 136 + c * 32 + q * 8);
      acc = __builtin_amdgcn_mfma_f32_16x16x32_bf16(afrag[c], bfrag, acc, 0, 0, 0);
    }
    int col = j * 16 + ln15;
#pragma unroll
    for (int rr = 0; rr < 4; rr++) {
      int m = r0 + rr;
      if (m < M) H8[(size_t)m * 128 + col] = f2fp8(dv[rr] * acc[rr]);
    }
  }
}

// ---------------- Aggregation: fp8 rows, 8 edges/pass, shfl-fed --------------
// out[i] = relu(b + dinv[i]*(Hs[i] + sum_{s in N(i)} Hs[s]))
__global__ __launch_bounds__(256) void k_agg(const uint4* __restrict__ Hs,  // fp8: 8 uint4/row
                                             const int* __restrict__ csr,
                                             const int* __restrict__ offs,
                                             const float* __restrict__ dinv,
                                             const float* __restrict__ bias,
                                             uint4* __restrict__ Ho,        // bf16: 16 uint4/row
                                             int n) {
  int lane = threadIdx.x & 63;
  int i = blockIdx.x * 4 + (threadIdx.x >> 6);
  if (i >= n) return;  // wave-uniform
  int oct = lane >> 3, k = lane & 7;
  int e0 = offs[i], e1 = offs[i + 1];
  int deg = e1 - e0;
  int adj = (lane < deg) ? csr[e0 + lane] : 0;

  float acc[16];
#pragma unroll
  for (int r = 0; r < 16; r++) acc[r] = 0.f;
  if (oct == 0) {  // self row
    uint4 h = Hs[(size_t)i * 8 + k];
    add16(acc, h);
  }
  int dcap = deg < 64 ? deg : 64;
  int j = 0;
#pragma unroll 2
  for (; j + 8 <= dcap; j += 8) {
    int s = __shfl(adj, j + oct);
    uint4 h = Hs[(size_t)s * 8 + k];
    add16(acc, h);
  }
  int rem = dcap - j;
  {
    int idx = j + oct;
    int s = __shfl(adj, idx < dcap ? idx : 0);
    if (oct < rem) {
      uint4 h = Hs[(size_t)s * 8 + k];
      add16(acc, h);
    }
  }
  // rare tail deg>64: direct csr loads
  for (int e = e0 + 64; e < e1; e += 8) {
    if (oct < e1 - e) {
      int s = csr[e + oct];
      uint4 h = Hs[(size_t)s * 8 + k];
      add16(acc, h);
    }
  }
  // reduce octs (xor 8, 16, 32)
#pragma unroll
  for (int r = 0; r < 16; r++) {
    acc[r] += __shfl_xor(acc[r], 8);
    acc[r] += __shfl_xor(acc[r], 16);
    acc[r] += __shfl_xor(acc[r], 32);
  }
  if (oct == 0) {
    float di = dinv[i];
    const float4* B4 = (const float4*)bias;  // feature f at B4[f>>2]
    float o[16];
#pragma unroll
    for (int m4 = 0; m4 < 4; m4++) {
      float4 b = B4[k * 4 + m4];
      o[m4 * 4 + 0] = fmaxf(b.x + di * acc[m4 * 4 + 0], 0.f);
      o[m4 * 4 + 1] = fmaxf(b.y + di * acc[m4 * 4 + 1], 0.f);
      o[m4 * 4 + 2] = fmaxf(b.z + di * acc[m4 * 4 + 2], 0.f);
      o[m4 * 4 + 3] = fmaxf(b.w + di * acc[m4 * 4 + 3], 0.f);
    }
    uint4 r0, r1;
    r0.x = pack2(o[0], o[1]);  r0.y = pack2(o[2], o[3]);
    r0.z = pack2(o[4], o[5]);  r0.w = pack2(o[6], o[7]);
    r1.x = pack2(o[8], o[9]);  r1.y = pack2(o[10], o[11]);
    r1.z = pack2(o[12], o[13]); r1.w = pack2(o[14], o[15]);
    Ho[(size_t)i * 16 + 2 * k] = r0;
    Ho[(size_t)i * 16 + 2 * k + 1] = r1;
  }
}

// ---------------- Node-parallel pool: segmented atomic sum (bf16 in) ----------
__global__ __launch_bounds__(256) void k_pool2(const unsigned* __restrict__ H2,
                                               const int* __restrict__ batch,
                                               float* __restrict__ ps, int n) {
  int t = threadIdx.x;
  int ln = t & 63, sub = t >> 6;
  int r0 = blockIdx.x * NPB + sub;
  int rend = min(blockIdx.x * NPB + NPB, n);
  float ax = 0.f, ay = 0.f;
  int curg = -1;
  for (int r = r0; r < rend; r += 4) {
    int g = batch[r];
    if (g != curg) {
      if (curg >= 0) {
        atomicAdd(&ps[curg * 128 + 2 * ln], ax);
        atomicAdd(&ps[curg * 128 + 2 * ln + 1], ay);
      }
      curg = g; ax = 0.f; ay = 0.f;
    }
    unsigned h = H2[(size_t)r * 64 + ln];
    ax += __uint_as_float(h << 16);
    ay += __uint_as_float(h & 0xffff0000u);
  }
  if (curg >= 0) {
    atomicAdd(&ps[curg * 128 + 2 * ln], ax);
    atomicAdd(&ps[curg * 128 + 2 * ln + 1], ay);
  }
}

// ---------------- Head: 512 blocks x 192 threads ----------------
__global__ void k_head(const float* __restrict__ ps, const int* __restrict__ gstart,
                       const float* __restrict__ axd,
                       const float* __restrict__ l1W, const float* __restrict__ l1b,
                       const float* __restrict__ axW, const float* __restrict__ axb,
                       const float* __restrict__ l2W, const float* __restrict__ l2b,
                       float* __restrict__ out) {
  int g = blockIdx.x, t = threadIdx.x;
  __shared__ float p[128];
  __shared__ float a[64];
  __shared__ float z[192];
  int c = gstart[g + 1] - gstart[g];
  if (c < 1) c = 1;
  float inv = 1.f / (float)c;
  if (t < 128) p[t] = ps[g * 128 + t] * inv;
  else a[t - 128] = axd[g * 64 + (t - 128)];
  __syncthreads();
  if (t < 128) {
    float acc = l1b[t];
#pragma unroll 4
    for (int kk = 0; kk < 128; kk++) acc += p[kk] * l1W[kk * 128 + t];
    z[t] = acc;
  } else {
    int j = t - 128;
    float acc = axb[j];
#pragma unroll 4
    for (int kk = 0; kk < 64; kk++) acc += a[kk] * axW[kk * 64 + j];
    z[128 + j] = acc;
  }
  __syncthreads();
  if (t < 8) {
    float acc = l2b[t];
#pragma unroll 4
    for (int kk = 0; kk < 192; kk++) acc += z[kk] * l2W[kk * 8 + t];
    out[g * 8 + t] = acc;
  }
}

extern "C" void kernel_launch(void* const* d_in, const int* in_sizes, int n_in,
                              void* d_out, int out_size, void* d_ws, size_t ws_size,
                              hipStream_t stream) {
  const float* x   = (const float*)d_in[0];
  const int*   ei  = (const int*)d_in[1];
  const int*   bat = (const int*)d_in[2];
  const float* axd = (const float*)d_in[3];
  const float* W1  = (const float*)d_in[4];
  const float* b1  = (const float*)d_in[5];
  const float* W2  = (const float*)d_in[6];
  const float* b2  = (const float*)d_in[7];
  const float* l1W = (const float*)d_in[8];
  const float* l1b = (const float*)d_in[9];
  const float* axW = (const float*)d_in[10];
  const float* axb = (const float*)d_in[11];
  const float* l2W = (const float*)d_in[12];
  const float* l2b = (const float*)d_in[13];
  float* out = (float*)d_out;

  int n = in_sizes[0] / NFEAT;   // 50000
  int E = in_sizes[1] / 2;       // 640000
  int G = in_sizes[3] / 64;      // 512

  unsigned char*  h8    = (unsigned char*)d_ws;                  // n*128 fp8
  unsigned short* habuf = (unsigned short*)(h8 + (size_t)n * 128); // n*128 bf16
  unsigned short* wt1   = habuf + (size_t)n * NFEAT;             // 16384 bf16
  unsigned short* wt2   = wt1 + 16384;                           // 16384 bf16
  int*   csr    = (int*)(wt2 + 16384);                           // E
  int*   offs   = csr + E;                                       // n+1
  int*   cursor = offs + (n + 1);                                // n
  int*   cnt    = cursor + n;                                    // n      (zeroed in prep)
  float* ps     = (float*)(cnt + n);                             // G*128  (zeroed in prep)
  float* dinv   = (float*)(ps + (size_t)G * 128);                // n
  int*   part   = (int*)(dinv + n);                              // 256
  int*   ppre   = part + 256;                                    // 256
  int*   gstart = ppre + 256;                                    // G+1

  const int* srcv = ei;
  const int* dstv = ei + E;
  int NB = (n + 255) / 256;
  int nb_cnt = NB;
  int nb_ps  = (G * 128 + 255) / 256;
  int nb_g   = (G + 1 + 255) / 256;
  int prep_blocks = nb_cnt + nb_ps + 128 + nb_g;

  k_prep<<<prep_blocks, 256, 0, stream>>>(W1, W2, wt1, wt2, bat, gstart, cnt, ps,
                                          n, G, nb_cnt, nb_ps);
  k_deg<<<(E + 255) / 256, 256, 0, stream>>>(dstv, cnt, E);
  k_part<<<NB, 256, 0, stream>>>(cnt, part, n);
  k_scan1<<<1, 256, 0, stream>>>(part, ppre, NB, offs, n);
  k_offsets<<<NB, 256, 0, stream>>>(cnt, ppre, offs, cursor, dinv, n);
  k_fill<<<(E + 255) / 256, 256, 0, stream>>>(srcv, dstv, cursor, csr, E);

  int gb = (n + 63) / 64;
  k_gemm_mfma<true><<<gb, 256, 0, stream>>>(x, (const uint4*)wt1, dinv, h8, n);
  k_agg<<<(n + 3) / 4, 256, 0, stream>>>((const uint4*)h8, csr, offs, dinv, b1,
                                         (uint4*)habuf, n);
  k_gemm_mfma<false><<<gb, 256, 0, stream>>>(habuf, (const uint4*)wt2, dinv, h8, n);
  k_agg<<<(n + 3) / 4, 256, 0, stream>>>((const uint4*)h8, csr, offs, dinv, b2,
                                         (uint4*)habuf, n);

  k_pool2<<<(n + NPB - 1) / NPB, 256, 0, stream>>>((const unsigned*)habuf, bat, ps, n);
  k_head<<<G, 192, 0, stream>>>(ps, gstart, axd, l1W, l1b, axW, axb, l2W, l2b, out);
}

// Round 7
// 296.149 us; speedup vs baseline: 1.0136x; 1.0136x over previous
//
#include <hip/hip_runtime.h>

// patient_GCN: 2x GCNConv(128->128) + mean-pool + head.
// R7: 8-way privatized atomics for CSR build (cnt8/cursor8 selected by
// blockIdx&7, consistent between deg and fill) -> ~8x less L2 RMW contention.
// Rest as R6: bf16 MFMA gemm (dinv folded), fp8 gather rows, shfl-fed agg.

#define NFEAT 128
#define NPB 128  // nodes per pool block

typedef __attribute__((ext_vector_type(8))) short bf16x8;
typedef __attribute__((ext_vector_type(4))) float f32x4;
typedef __attribute__((ext_vector_type(2))) float f32x2;

static __device__ __forceinline__ unsigned short f2bf(float f) {
  unsigned u = __float_as_uint(f);
  return (unsigned short)((u + 0x7fffu + ((u >> 16) & 1u)) >> 16);
}
static __device__ __forceinline__ unsigned pack2(float a, float b) {
  return (unsigned)f2bf(a) | ((unsigned)f2bf(b) << 16);
}
static __device__ __forceinline__ unsigned char f2fp8(float v) {
  return (unsigned char)(__builtin_amdgcn_cvt_pk_fp8_f32(v, 0.f, 0, false) & 0xff);
}
static __device__ __forceinline__ void add16(float* a, uint4 h) {
  f32x2 t;
  t = __builtin_amdgcn_cvt_pk_f32_fp8(h.x, false); a[0] += t[0]; a[1] += t[1];
  t = __builtin_amdgcn_cvt_pk_f32_fp8(h.x, true);  a[2] += t[0]; a[3] += t[1];
  t = __builtin_amdgcn_cvt_pk_f32_fp8(h.y, false); a[4] += t[0]; a[5] += t[1];
  t = __builtin_amdgcn_cvt_pk_f32_fp8(h.y, true);  a[6] += t[0]; a[7] += t[1];
  t = __builtin_amdgcn_cvt_pk_f32_fp8(h.z, false); a[8] += t[0]; a[9] += t[1];
  t = __builtin_amdgcn_cvt_pk_f32_fp8(h.z, true);  a[10] += t[0]; a[11] += t[1];
  t = __builtin_amdgcn_cvt_pk_f32_fp8(h.w, false); a[12] += t[0]; a[13] += t[1];
  t = __builtin_amdgcn_cvt_pk_f32_fp8(h.w, true);  a[14] += t[0]; a[15] += t[1];
}

// ---------------- prep: zero cnt8+ps, transpose W1/W2 to bf16, graph bounds ---
__global__ void k_prep(const float* __restrict__ W1, const float* __restrict__ W2,
                       unsigned short* __restrict__ WT1, unsigned short* __restrict__ WT2,
                       const int* __restrict__ batch, int* __restrict__ gstart,
                       int* __restrict__ cnt8, float* __restrict__ ps,
                       int n, int G, int nb_cnt, int nb_ps) {
  int b = blockIdx.x, t = threadIdx.x;
  if (b < nb_cnt) {
    int i = b * 256 + t;
    if (i < 8 * n) cnt8[i] = 0;
  } else if (b < nb_cnt + nb_ps) {
    int i = (b - nb_cnt) * 256 + t;
    if (i < G * 128) ps[i] = 0.f;
  } else if (b < nb_cnt + nb_ps + 128) {
    int e = (b - nb_cnt - nb_ps) * 256 + t;  // 32768 total
    int w = e >> 14;
    int r = (e >> 7) & 127, k = e & 127;
    if (w == 0) WT1[r * 128 + k] = f2bf(W1[k * 128 + r]);
    else        WT2[r * 128 + k] = f2bf(W2[k * 128 + r]);
  } else {
    int g = (b - nb_cnt - nb_ps - 128) * 256 + t;
    if (g > G) return;
    if (g == G) { gstart[g] = n; return; }
    int lo = 0, hi = n;
    while (lo < hi) {
      int mid = (lo + hi) >> 1;
      if (batch[mid] < g) lo = mid + 1; else hi = mid;
    }
    gstart[g] = lo;
  }
}

// ---------------- CSR build (8-way privatized) ----------------
__global__ void k_deg(const int* __restrict__ dst, int* __restrict__ cnt8,
                      int E, int n) {
  int e = blockIdx.x * 256 + threadIdx.x;
  int c = blockIdx.x & 7;
  if (e < E) atomicAdd(&cnt8[c * n + dst[e]], 1);
}

// block partials over per-node TOTALS (sum of 8 copies)
__global__ void k_part(const int* __restrict__ cnt8, int* __restrict__ part,
                       int n) {
  __shared__ int s[256];
  int t = threadIdx.x;
  int idx = blockIdx.x * 256 + t;
  int v = 0;
  if (idx < n) {
#pragma unroll
    for (int c = 0; c < 8; c++) v += cnt8[c * n + idx];
  }
  s[t] = v;
  __syncthreads();
  for (int o = 128; o > 0; o >>= 1) {
    if (t < o) s[t] += s[t + o];
    __syncthreads();
  }
  if (t == 0) part[blockIdx.x] = s[0];
}

__global__ void k_scan1(const int* __restrict__ part, int* __restrict__ ppre,
                        int NB, int* __restrict__ offs, int n) {
  __shared__ int s[256];
  int t = threadIdx.x;
  int v = (t < NB) ? part[t] : 0;
  s[t] = v;
  __syncthreads();
  for (int o = 1; o < 256; o <<= 1) {
    int tmp = (t >= o) ? s[t - o] : 0;
    __syncthreads();
    s[t] += tmp;
    __syncthreads();
  }
  if (t < NB) ppre[t] = s[t] - v;
  if (t == NB - 1) offs[n] = s[t];
}

// offsets + 8 segment cursors + dinv
__global__ void k_offsets(const int* __restrict__ cnt8, const int* __restrict__ ppre,
                          int* __restrict__ offs, int* __restrict__ cursor8,
                          float* __restrict__ dinv, int n) {
  __shared__ int s[256];
  int t = threadIdx.x;
  int idx = blockIdx.x * 256 + t;
  int vc[8];
  int tot = 0;
  if (idx < n) {
#pragma unroll
    for (int c = 0; c < 8; c++) { vc[c] = cnt8[c * n + idx]; tot += vc[c]; }
  }
  s[t] = tot;
  __syncthreads();
  for (int o = 1; o < 256; o <<= 1) {
    int tmp = (t >= o) ? s[t - o] : 0;
    __syncthreads();
    s[t] += tmp;
    __syncthreads();
  }
  if (idx < n) {
    int off = ppre[blockIdx.x] + s[t] - tot;
    offs[idx] = off;
    int run = off;
#pragma unroll
    for (int c = 0; c < 8; c++) { cursor8[c * n + idx] = run; run += vc[c]; }
    dinv[idx] = rsqrtf((float)(tot + 1));
  }
}

__global__ void k_fill(const int* __restrict__ src, const int* __restrict__ dst,
                       int* __restrict__ cursor8, int* __restrict__ csr,
                       int E, int n) {
  int e = blockIdx.x * 256 + threadIdx.x;
  int c = blockIdx.x & 7;
  if (e < E) {
    int p = atomicAdd(&cursor8[c * n + dst[e]], 1);
    csr[p] = src[e];
  }
}

// ---------------- GEMM: Hs[M,128](fp8) = dinv[m] * (X[M,128] @ W) ----------------
template <bool FP32IN>
__global__ __launch_bounds__(256) void k_gemm_mfma(const void* __restrict__ Xv,
                                                   const uint4* __restrict__ WT4,
                                                   const float* __restrict__ dinv,
                                                   unsigned char* __restrict__ H8,
                                                   int M) {
  __shared__ __align__(16) unsigned short sW[128 * 136];
  __shared__ __align__(16) unsigned short sX[64 * 136];
  int tid = threadIdx.x;
  int m0 = blockIdx.x * 64;

#pragma unroll
  for (int t = 0; t < 8; t++) {
    int idx = tid + t * 256;
    int n = idx >> 4, c8 = idx & 15;
    *(uint4*)(sW + n * 136 + c8 * 8) = WT4[idx];
  }
  if (FP32IN) {
    const float4* X4 = (const float4*)Xv;
#pragma unroll
    for (int t = 0; t < 8; t++) {
      int idx = tid + t * 256;
      int r = idx >> 5, c4 = idx & 31;
      int m = m0 + r;
      float4 v = make_float4(0.f, 0.f, 0.f, 0.f);
      if (m < M) v = X4[(size_t)m * 32 + c4];
      unsigned short* p = sX + r * 136 + c4 * 4;
      *(ushort2*)(p) = make_ushort2(f2bf(v.x), f2bf(v.y));
      *(ushort2*)(p + 2) = make_ushort2(f2bf(v.z), f2bf(v.w));
    }
  } else {
    const uint4* X4 = (const uint4*)Xv;
#pragma unroll
    for (int t = 0; t < 4; t++) {
      int idx = tid + t * 256;
      int r = idx >> 4, c8 = idx & 15;
      int m = m0 + r;
      uint4 v = make_uint4(0u, 0u, 0u, 0u);
      if (m < M) v = X4[(size_t)m * 16 + c8];
      *(uint4*)(sX + r * 136 + c8 * 8) = v;
    }
  }
  __syncthreads();

  int lane = tid & 63, wv = tid >> 6;
  int ln15 = lane & 15, q = lane >> 4;
  bf16x8 afrag[4];
#pragma unroll
  for (int c = 0; c < 4; c++)
    afrag[c] = *(const bf16x8*)(sX + (wv * 16 + ln15) * 136 + c * 32 + q * 8);

  int r0 = m0 + wv * 16 + q * 4;
  float dv[4];
#pragma unroll
  for (int rr = 0; rr < 4; rr++) dv[rr] = (r0 + rr < M) ? dinv[r0 + rr] : 0.f;

#pragma unroll
  for (int j = 0; j < 8; j++) {
    f32x4 acc = {0.f, 0.f, 0.f, 0.f};
#pragma unroll
    for (int c = 0; c < 4; c++) {
      bf16x8 bfrag = *(const bf16x8*)(sW + (j * 16 + ln15) * 136 + c * 32 + q * 8);
      acc = __builtin_amdgcn_mfma_f32_16x16x32_bf16(afrag[c], bfrag, acc, 0, 0, 0);
    }
    int col = j * 16 + ln15;
#pragma unroll
    for (int rr = 0; rr < 4; rr++) {
      int m = r0 + rr;
      if (m < M) H8[(size_t)m * 128 + col] = f2fp8(dv[rr] * acc[rr]);
    }
  }
}

// ---------------- Aggregation: fp8 rows, 8 edges/pass, shfl-fed --------------
__global__ __launch_bounds__(256) void k_agg(const uint4* __restrict__ Hs,  // fp8: 8 uint4/row
                                             const int* __restrict__ csr,
                                             const int* __restrict__ offs,
                                             const float* __restrict__ dinv,
                                             const float* __restrict__ bias,
                                             uint4* __restrict__ Ho,        // bf16: 16 uint4/row
                                             int n) {
  int lane = threadIdx.x & 63;
  int i = blockIdx.x * 4 + (threadIdx.x >> 6);
  if (i >= n) return;  // wave-uniform
  int oct = lane >> 3, k = lane & 7;
  int e0 = offs[i], e1 = offs[i + 1];
  int deg = e1 - e0;
  int adj = (lane < deg) ? csr[e0 + lane] : 0;

  float acc[16];
#pragma unroll
  for (int r = 0; r < 16; r++) acc[r] = 0.f;
  if (oct == 0) {  // self row
    uint4 h = Hs[(size_t)i * 8 + k];
    add16(acc, h);
  }
  int dcap = deg < 64 ? deg : 64;
  int j = 0;
#pragma unroll 2
  for (; j + 8 <= dcap; j += 8) {
    int s = __shfl(adj, j + oct);
    uint4 h = Hs[(size_t)s * 8 + k];
    add16(acc, h);
  }
  int rem = dcap - j;
  {
    int idx = j + oct;
    int s = __shfl(adj, idx < dcap ? idx : 0);
    if (oct < rem) {
      uint4 h = Hs[(size_t)s * 8 + k];
      add16(acc, h);
    }
  }
  for (int e = e0 + 64; e < e1; e += 8) {
    if (oct < e1 - e) {
      int s = csr[e + oct];
      uint4 h = Hs[(size_t)s * 8 + k];
      add16(acc, h);
    }
  }
#pragma unroll
  for (int r = 0; r < 16; r++) {
    acc[r] += __shfl_xor(acc[r], 8);
    acc[r] += __shfl_xor(acc[r], 16);
    acc[r] += __shfl_xor(acc[r], 32);
  }
  if (oct == 0) {
    float di = dinv[i];
    const float4* B4 = (const float4*)bias;
    float o[16];
#pragma unroll
    for (int m4 = 0; m4 < 4; m4++) {
      float4 b = B4[k * 4 + m4];
      o[m4 * 4 + 0] = fmaxf(b.x + di * acc[m4 * 4 + 0], 0.f);
      o[m4 * 4 + 1] = fmaxf(b.y + di * acc[m4 * 4 + 1], 0.f);
      o[m4 * 4 + 2] = fmaxf(b.z + di * acc[m4 * 4 + 2], 0.f);
      o[m4 * 4 + 3] = fmaxf(b.w + di * acc[m4 * 4 + 3], 0.f);
    }
    uint4 r0, r1;
    r0.x = pack2(o[0], o[1]);  r0.y = pack2(o[2], o[3]);
    r0.z = pack2(o[4], o[5]);  r0.w = pack2(o[6], o[7]);
    r1.x = pack2(o[8], o[9]);  r1.y = pack2(o[10], o[11]);
    r1.z = pack2(o[12], o[13]); r1.w = pack2(o[14], o[15]);
    Ho[(size_t)i * 16 + 2 * k] = r0;
    Ho[(size_t)i * 16 + 2 * k + 1] = r1;
  }
}

// ---------------- Node-parallel pool: segmented atomic sum (bf16 in) ----------
__global__ __launch_bounds__(256) void k_pool2(const unsigned* __restrict__ H2,
                                               const int* __restrict__ batch,
                                               float* __restrict__ ps, int n) {
  int t = threadIdx.x;
  int ln = t & 63, sub = t >> 6;
  int r0 = blockIdx.x * NPB + sub;
  int rend = min(blockIdx.x * NPB + NPB, n);
  float ax = 0.f, ay = 0.f;
  int curg = -1;
  for (int r = r0; r < rend; r += 4) {
    int g = batch[r];
    if (g != curg) {
      if (curg >= 0) {
        atomicAdd(&ps[curg * 128 + 2 * ln], ax);
        atomicAdd(&ps[curg * 128 + 2 * ln + 1], ay);
      }
      curg = g; ax = 0.f; ay = 0.f;
    }
    unsigned h = H2[(size_t)r * 64 + ln];
    ax += __uint_as_float(h << 16);
    ay += __uint_as_float(h & 0xffff0000u);
  }
  if (curg >= 0) {
    atomicAdd(&ps[curg * 128 + 2 * ln], ax);
    atomicAdd(&ps[curg * 128 + 2 * ln + 1], ay);
  }
}

// ---------------- Head: 512 blocks x 192 threads ----------------
__global__ void k_head(const float* __restrict__ ps, const int* __restrict__ gstart,
                       const float* __restrict__ axd,
                       const float* __restrict__ l1W, const float* __restrict__ l1b,
                       const float* __restrict__ axW, const float* __restrict__ axb,
                       const float* __restrict__ l2W, const float* __restrict__ l2b,
                       float* __restrict__ out) {
  int g = blockIdx.x, t = threadIdx.x;
  __shared__ float p[128];
  __shared__ float a[64];
  __shared__ float z[192];
  int c = gstart[g + 1] - gstart[g];
  if (c < 1) c = 1;
  float inv = 1.f / (float)c;
  if (t < 128) p[t] = ps[g * 128 + t] * inv;
  else a[t - 128] = axd[g * 64 + (t - 128)];
  __syncthreads();
  if (t < 128) {
    float acc = l1b[t];
#pragma unroll 4
    for (int kk = 0; kk < 128; kk++) acc += p[kk] * l1W[kk * 128 + t];
    z[t] = acc;
  } else {
    int j = t - 128;
    float acc = axb[j];
#pragma unroll 4
    for (int kk = 0; kk < 64; kk++) acc += a[kk] * axW[kk * 64 + j];
    z[128 + j] = acc;
  }
  __syncthreads();
  if (t < 8) {
    float acc = l2b[t];
#pragma unroll 4
    for (int kk = 0; kk < 192; kk++) acc += z[kk] * l2W[kk * 8 + t];
    out[g * 8 + t] = acc;
  }
}

extern "C" void kernel_launch(void* const* d_in, const int* in_sizes, int n_in,
                              void* d_out, int out_size, void* d_ws, size_t ws_size,
                              hipStream_t stream) {
  const float* x   = (const float*)d_in[0];
  const int*   ei  = (const int*)d_in[1];
  const int*   bat = (const int*)d_in[2];
  const float* axd = (const float*)d_in[3];
  const float* W1  = (const float*)d_in[4];
  const float* b1  = (const float*)d_in[5];
  const float* W2  = (const float*)d_in[6];
  const float* b2  = (const float*)d_in[7];
  const float* l1W = (const float*)d_in[8];
  const float* l1b = (const float*)d_in[9];
  const float* axW = (const float*)d_in[10];
  const float* axb = (const float*)d_in[11];
  const float* l2W = (const float*)d_in[12];
  const float* l2b = (const float*)d_in[13];
  float* out = (float*)d_out;

  int n = in_sizes[0] / NFEAT;   // 50000
  int E = in_sizes[1] / 2;       // 640000
  int G = in_sizes[3] / 64;      // 512

  unsigned char*  h8    = (unsigned char*)d_ws;                    // n*128 fp8
  unsigned short* habuf = (unsigned short*)(h8 + (size_t)n * 128); // n*128 bf16
  unsigned short* wt1   = habuf + (size_t)n * NFEAT;               // 16384 bf16
  unsigned short* wt2   = wt1 + 16384;                             // 16384 bf16
  int*   csr     = (int*)(wt2 + 16384);                            // E
  int*   offs    = csr + E;                                        // n+1
  int*   cursor8 = offs + (n + 1);                                 // 8n
  int*   cnt8    = cursor8 + 8 * n;                                // 8n  (zeroed in prep)
  float* ps      = (float*)(cnt8 + 8 * n);                         // G*128 (zeroed in prep)
  float* dinv    = (float*)(ps + (size_t)G * 128);                 // n
  int*   part    = (int*)(dinv + n);                               // 256
  int*   ppre    = part + 256;                                     // 256
  int*   gstart  = ppre + 256;                                     // G+1

  const int* srcv = ei;
  const int* dstv = ei + E;
  int NB = (n + 255) / 256;
  int nb_cnt = (8 * n + 255) / 256;      // zero cnt8
  int nb_ps  = (G * 128 + 255) / 256;    // zero ps
  int nb_g   = (G + 1 + 255) / 256;      // gbounds
  int prep_blocks = nb_cnt + nb_ps + 128 + nb_g;

  k_prep<<<prep_blocks, 256, 0, stream>>>(W1, W2, wt1, wt2, bat, gstart, cnt8, ps,
                                          n, G, nb_cnt, nb_ps);
  k_deg<<<(E + 255) / 256, 256, 0, stream>>>(dstv, cnt8, E, n);
  k_part<<<NB, 256, 0, stream>>>(cnt8, part, n);
  k_scan1<<<1, 256, 0, stream>>>(part, ppre, NB, offs, n);
  k_offsets<<<NB, 256, 0, stream>>>(cnt8, ppre, offs, cursor8, dinv, n);
  k_fill<<<(E + 255) / 256, 256, 0, stream>>>(srcv, dstv, cursor8, csr, E, n);

  int gb = (n + 63) / 64;
  k_gemm_mfma<true><<<gb, 256, 0, stream>>>(x, (const uint4*)wt1, dinv, h8, n);
  k_agg<<<(n + 3) / 4, 256, 0, stream>>>((const uint4*)h8, csr, offs, dinv, b1,
                                         (uint4*)habuf, n);
  k_gemm_mfma<false><<<gb, 256, 0, stream>>>(habuf, (const uint4*)wt2, dinv, h8, n);
  k_agg<<<(n + 3) / 4, 256, 0, stream>>>((const uint4*)h8, csr, offs, dinv, b2,
                                         (uint4*)habuf, n);

  k_pool2<<<(n + NPB - 1) / NPB, 256, 0, stream>>>((const unsigned*)habuf, bat, ps, n);
  k_head<<<G, 192, 0, stream>>>(ps, gstart, axd, l1W, l1b, axW, axb, l2W, l2b, out);
}